// Round 9
// baseline (1046.070 us; speedup 1.0000x reference)
//
#include <hip/hip_runtime.h>
#include <math.h>

#define TOKENS    1024
#define IN_W      512
#define BLOCK_H   256
#define OUT_W     512
#define N_EXPERTS 64
#define TOPK      2
#define NSLOTS    (TOKENS * TOPK)
#define LIST_CAP  128     // ne ~ Binom(2048,1/64): mean 32, sigma 5.6
#define T_GRP     16      // tokens per chunk
#define NCHS      2       // chunk-slots (covers ne<=32 in one pass each)
#define NQ        4       // hidden-dim quarters -> 64*2*4 = 512 blocks, ALL active
#define XPAD      520     // x row stride (floats); 2080 B, 16B-aligned
#define VS        68      // v row stride (64 + 4), 16B-aligned

// ---------------------------------------------------------------------------
// Routing + fused compaction (unchanged from round 5; ~4 us).
// ---------------------------------------------------------------------------
__global__ __launch_bounds__(256) void routing_kernel(
    const float* __restrict__ x, const float* __restrict__ noise,
    const float* __restrict__ mixer, const float* __restrict__ noisec,
    float* __restrict__ esc, int* __restrict__ counts, int* __restrict__ lists)
{
    __shared__ float xs[2 * 512];
    __shared__ float pm[2 * 2 * 64];
    __shared__ float pn[2 * 2 * 64];
    const int blk  = blockIdx.x;
    const int tid  = threadIdx.x;
    const int wave = tid >> 6, lane = tid & 63;
    const int tq = wave >> 1;
    const int ih = wave & 1;

    ((float4*)xs)[tid] = ((const float4*)x)[(size_t)blk * 256 + tid];
    __syncthreads();

    float am = 0.f, an = 0.f;
    const float* xp = xs + tq * 512 + ih * 256;
    const float* mp = mixer  + (size_t)(ih * 256) * 64 + lane;
    const float* np = noisec + (size_t)(ih * 256) * 64 + lane;
    #pragma unroll 8
    for (int i = 0; i < 256; ++i) {
        const float xv = xp[i];
        am = fmaf(xv, mp[i * 64], am);
        an = fmaf(xv, np[i * 64], an);
    }
    pm[tq * 128 + ih * 64 + lane] = am;
    pn[tq * 128 + ih * 64 + lane] = an;
    __syncthreads();

    if (tid < 128) {
        const int e = tid & 63, tt = tid >> 6;
        const int t = blk * 2 + tt;
        const float am2 = pm[tt * 128 + e] + pm[tt * 128 + 64 + e];
        const float an2 = pn[tt * 128 + e] + pn[tt * 128 + 64 + e];
        const float sp = fmaxf(an2, 0.f) + log1pf(expf(-fabsf(an2)));
        pm[tt * 128 + e] = am2 + noise[(size_t)t * 64 + e] * sp;
    }
    __syncthreads();

    if (tid < 2) {
        const float* h = pm + tid * 128;
        float b0 = -INFINITY, b1 = -INFINITY;
        int i0 = 0, i1 = 0;
        for (int i = 0; i < N_EXPERTS; ++i) {
            const float v = h[i];
            if (v > b0)      { b1 = b0; i1 = i0; b0 = v; i0 = i; }  // strict >: stable ties
            else if (v > b1) { b1 = v; i1 = i; }
        }
        const float z   = expf(b1 - b0);
        const float inv = 1.f / (1.f + z);
        const int t = blk * 2 + tid;
        esc[t * 2 + 0] = inv;
        esc[t * 2 + 1] = z * inv;
        const int p0 = atomicAdd(&counts[i0], 1);
        if (p0 < LIST_CAP) lists[i0 * LIST_CAP + p0] = t * 2 + 0;
        const int p1 = atomicAdd(&counts[i1], 1);
        if (p1 < LIST_CAP) lists[i1 * LIST_CAP + p1] = t * 2 + 1;
    }
}

// ---------------------------------------------------------------------------
// Fused expert FFN, round 9: HIDDEN-QUARTER blocks.
// grid (64 experts, 2 chunk-slots, 4 quarters) = 512 blocks, 512 threads,
// 2 blocks/CU resident -> 4 waves/SIMD (the variable that tracked perf in
// R4/R5/R6/R8), and NO idle groups for typical ne (16 < ne <= 32 -> every
// (cs,q) block has work). Every weight byte read ONCE across the grid:
//   phase 1: v_q = relu(x @ W1[:, q*64:+64] + b1_q); wave = 64 K-rows,
//     lane = column (scalar acc[16] tokens). 8-wave K-partials via ds_add.
//   phase 2: partial out = v_q @ W2[q*64:+64, :]; wave = 64 out-cols,
//     lane = column; epilogue atomicAdd of sc*(acc + b2*[q==0]).
// Weight loads: 64 lanes x 4 B = 256 B/instr (R5 vs R6 showed load width
// is not the limiter); 16 FMA per weight scalar; 4-deep prefetch ring.
// ---------------------------------------------------------------------------
__global__ __launch_bounds__(512, 4) void expert_kernel(
    const float* __restrict__ x,
    const float* __restrict__ w1s, const float* __restrict__ b1s,
    const float* __restrict__ w2s, const float* __restrict__ b2s,
    const int* __restrict__ counts, const int* __restrict__ lists,
    const float* __restrict__ esc, float* __restrict__ out)
{
    __shared__ __align__(16) float xs [T_GRP * XPAD];   // 33.3 KB
    __shared__ __align__(16) float vsm[T_GRP * VS];     //  4.4 KB
    __shared__ int   slotIds[T_GRP];
    __shared__ float escv[T_GRP];

    const int e  = blockIdx.x;
    const int cs = blockIdx.y;           // chunk-slot
    const int q  = blockIdx.z;           // hidden quarter
    const int ne = min(counts[e], LIST_CAP);
    const int nChunks = (ne + T_GRP - 1) / T_GRP;
    const int tid  = threadIdx.x;
    const int wave = tid >> 6, lane = tid & 63;

    // phase-1: col = q*64 + lane of W1's 256; row stride 256 floats
    const float* w1p = w1s + (size_t)e * IN_W * BLOCK_H + q * 64 + lane;
    // phase-2: col = wave*64 + lane of W2's 512; rows q*64..+64
    const float* w2p = w2s + (size_t)e * BLOCK_H * OUT_W
                     + (size_t)(q * 64) * OUT_W + wave * 64 + lane;
    const float  b1c = b1s[(size_t)e * BLOCK_H + q * 64 + lane];   // lane's col
    const float  b2c = b2s[(size_t)e * OUT_W + wave * 64 + lane];
    const float4* x4 = (const float4*)x;

    for (int ci = cs; ci < nChunks; ci += NCHS) {
        const int base = ci * T_GRP;
        const int nTok = min(T_GRP, ne - base);
        if (tid < T_GRP) {
            const int s = (tid < nTok) ? lists[e * LIST_CAP + base + tid] : 0;
            slotIds[tid] = s;
            escv[tid]    = esc[s];
        }
        for (int i = tid; i < T_GRP * VS; i += 512) vsm[i] = 0.f;
        __syncthreads();

        // stage 16 token rows (zero-pad missing)
        for (int idx = tid; idx < T_GRP * 128; idx += 512) {
            const int t = idx >> 7, c = idx & 127;
            float4 v = make_float4(0.f, 0.f, 0.f, 0.f);
            if (t < nTok) v = x4[(size_t)(slotIds[t] >> 1) * 128 + c];
            *(float4*)&xs[t * XPAD + c * 4] = v;
        }
        __syncthreads();

        // ---- phase 1: wave's 64 K-rows of W1 col-quarter ----
        {
            float acc[T_GRP];
            #pragma unroll
            for (int t = 0; t < T_GRP; ++t) acc[t] = 0.f;
            const int r0 = wave * 64;
            const float* wp = w1p + (size_t)r0 * BLOCK_H;
            float wb[4];
            #pragma unroll
            for (int k = 0; k < 4; ++k) wb[k] = wp[(size_t)k * BLOCK_H];
            for (int r = 0; r < 64; r += 4) {
                float wc[4];
                #pragma unroll
                for (int k = 0; k < 4; ++k) wc[k] = wb[k];
                if (r + 4 < 64) {
                    #pragma unroll
                    for (int k = 0; k < 4; ++k)
                        wb[k] = wp[(size_t)(r + 4 + k) * BLOCK_H];
                }
                #pragma unroll
                for (int t = 0; t < T_GRP; ++t) {
                    const float4 xv = *(const float4*)&xs[t * XPAD + r0 + r];
                    acc[t] = fmaf(xv.x, wc[0], acc[t]);
                    acc[t] = fmaf(xv.y, wc[1], acc[t]);
                    acc[t] = fmaf(xv.z, wc[2], acc[t]);
                    acc[t] = fmaf(xv.w, wc[3], acc[t]);
                }
            }
            #pragma unroll
            for (int t = 0; t < T_GRP; ++t)
                atomicAdd(&vsm[t * VS + lane], acc[t]);   // 2-way banks: free
        }
        __syncthreads();

        // ---- bias + ReLU on v-quarter ----
        for (int idx = tid; idx < T_GRP * 64; idx += 512) {
            const int t = idx >> 6, c = idx & 63;
            const float bb = b1s[(size_t)e * BLOCK_H + q * 64 + c];
            vsm[t * VS + c] = fmaxf(vsm[t * VS + c] + bb, 0.f);
        }
        __syncthreads();

        // ---- phase 2: wave's 64 out-cols, K = quarter's 64 h-rows ----
        {
            float acc[T_GRP];
            #pragma unroll
            for (int t = 0; t < T_GRP; ++t) acc[t] = 0.f;
            float wb[4];
            #pragma unroll
            for (int k = 0; k < 4; ++k) wb[k] = w2p[(size_t)k * OUT_W];
            for (int h = 0; h < 64; h += 4) {
                float wc[4];
                #pragma unroll
                for (int k = 0; k < 4; ++k) wc[k] = wb[k];
                if (h + 4 < 64) {
                    #pragma unroll
                    for (int k = 0; k < 4; ++k)
                        wb[k] = w2p[(size_t)(h + 4 + k) * OUT_W];
                }
                #pragma unroll
                for (int t = 0; t < T_GRP; ++t) {
                    const float4 vv = *(const float4*)&vsm[t * VS + h];
                    acc[t] = fmaf(vv.x, wc[0], acc[t]);
                    acc[t] = fmaf(vv.y, wc[1], acc[t]);
                    acc[t] = fmaf(vv.z, wc[2], acc[t]);
                    acc[t] = fmaf(vv.w, wc[3], acc[t]);
                }
            }
            // epilogue: out += sc * (acc + b2 [q==0 only])
            const float badd = (q == 0) ? b2c : 0.f;
            const int   col  = wave * 64 + lane;
            #pragma unroll
            for (int t = 0; t < T_GRP; ++t) {
                if (t < nTok) {
                    const float sc = escv[t];
                    atomicAdd(out + (size_t)(slotIds[t] >> 1) * OUT_W + col,
                              (acc[t] + badd) * sc);
                }
            }
        }
        __syncthreads();   // buffers reused next chunk (ne > 32 only)
    }
}

extern "C" void kernel_launch(void* const* d_in, const int* in_sizes, int n_in,
                              void* d_out, int out_size, void* d_ws, size_t ws_size,
                              hipStream_t stream) {
    const float* x      = (const float*)d_in[0];
    const float* noise  = (const float*)d_in[1];
    const float* w1s    = (const float*)d_in[2];
    const float* b1s    = (const float*)d_in[3];
    const float* w2s    = (const float*)d_in[4];
    const float* b2s    = (const float*)d_in[5];
    const float* mixer  = (const float*)d_in[6];
    const float* noisec = (const float*)d_in[7];
    float* out = (float*)d_out;

    // workspace: ~41 KB total (keep far under ws_size; round 2's 2.2 MB
    // layout overran d_ws and corrupted adjacent allocations)
    char* ws = (char*)d_ws;
    int*   counts = (int*)ws;                       ws += 256;
    float* esc    = (float*)ws;                     ws += NSLOTS * sizeof(float);
    int*   lists  = (int*)ws;   /* 64 * 128 ints = 32 KB */

    hipMemsetAsync(d_out, 0, (size_t)out_size * sizeof(float), stream);
    hipMemsetAsync(counts, 0, 256, stream);

    routing_kernel<<<TOKENS / 2, 256, 0, stream>>>(x, noise, mixer, noisec,
                                                   esc, counts, lists);
    expert_kernel<<<dim3(N_EXPERTS, NCHS, NQ), 512, 0, stream>>>(
        x, w1s, b1s, w2s, b2s, counts, lists, esc, out);
}

// Round 10
// 211.428 us; speedup vs baseline: 4.9476x; 4.9476x over previous
//
#include <hip/hip_runtime.h>
#include <math.h>

#define TOKENS    1024
#define IN_W      512
#define BLOCK_H   256
#define OUT_W     512
#define N_EXPERTS 64
#define TOPK      2
#define NSLOTS    (TOKENS * TOPK)
#define LIST_CAP  128     // ne ~ Binom(2048,1/64): mean 32, sigma 5.6
#define T_GRP     8       // tokens per chunk
#define NCS       4       // chunk-slots -> 64*4 = 256 blocks, all active for ne>24
#define XPAD      512     // x row stride (floats); broadcast reads, no pad needed
#define VPAD      260     // v row stride (floats)
#define W1PAD     260     // staged W1 bf16 row stride (256+4: rotates banks by 8/row-grp)
#define W2PAD     516     // staged W2 bf16 row stride (512+4)
#define KS1       32      // W1 slab rows  (16 slabs)
#define KS2       16      // W2 slab rows  (16 slabs)
#define NSLAB     32
#define WBUF_SZ   (KS1 * W1PAD)   // 8320 ushorts = 16.6 KB (>= KS2*W2PAD = 8256)

__device__ __forceinline__ void fma4(float4& a, float s, float w0, float w1,
                                     float w2, float w3) {
    a.x = fmaf(s, w0, a.x); a.y = fmaf(s, w1, a.y);
    a.z = fmaf(s, w2, a.z); a.w = fmaf(s, w3, a.w);
}
__device__ __forceinline__ unsigned bf16rne(float f) {
    unsigned u = __float_as_uint(f);
    return (u + 0x7FFFu + ((u >> 16) & 1u)) >> 16;
}
__device__ __forceinline__ uint2 packf4(float4 v) {
    return make_uint2(bf16rne(v.x) | (bf16rne(v.y) << 16),
                      bf16rne(v.z) | (bf16rne(v.w) << 16));
}

// ---------------------------------------------------------------------------
// Routing + fused compaction (unchanged from round 5; ~4 us).
// ---------------------------------------------------------------------------
__global__ __launch_bounds__(256) void routing_kernel(
    const float* __restrict__ x, const float* __restrict__ noise,
    const float* __restrict__ mixer, const float* __restrict__ noisec,
    float* __restrict__ esc, int* __restrict__ counts, int* __restrict__ lists)
{
    __shared__ float xs[2 * 512];
    __shared__ float pm[2 * 2 * 64];
    __shared__ float pn[2 * 2 * 64];
    const int blk  = blockIdx.x;
    const int tid  = threadIdx.x;
    const int wave = tid >> 6, lane = tid & 63;
    const int tq = wave >> 1;
    const int ih = wave & 1;

    ((float4*)xs)[tid] = ((const float4*)x)[(size_t)blk * 256 + tid];
    __syncthreads();

    float am = 0.f, an = 0.f;
    const float* xp = xs + tq * 512 + ih * 256;
    const float* mp = mixer  + (size_t)(ih * 256) * 64 + lane;
    const float* np = noisec + (size_t)(ih * 256) * 64 + lane;
    #pragma unroll 8
    for (int i = 0; i < 256; ++i) {
        const float xv = xp[i];
        am = fmaf(xv, mp[i * 64], am);
        an = fmaf(xv, np[i * 64], an);
    }
    pm[tq * 128 + ih * 64 + lane] = am;
    pn[tq * 128 + ih * 64 + lane] = an;
    __syncthreads();

    if (tid < 128) {
        const int e = tid & 63, tt = tid >> 6;
        const int t = blk * 2 + tt;
        const float am2 = pm[tt * 128 + e] + pm[tt * 128 + 64 + e];
        const float an2 = pn[tt * 128 + e] + pn[tt * 128 + 64 + e];
        const float sp = fmaxf(an2, 0.f) + log1pf(expf(-fabsf(an2)));
        pm[tt * 128 + e] = am2 + noise[(size_t)t * 64 + e] * sp;
    }
    __syncthreads();

    if (tid < 2) {
        const float* h = pm + tid * 128;
        float b0 = -INFINITY, b1 = -INFINITY;
        int i0 = 0, i1 = 0;
        for (int i = 0; i < N_EXPERTS; ++i) {
            const float v = h[i];
            if (v > b0)      { b1 = b0; i1 = i0; b0 = v; i0 = i; }  // strict >: stable ties
            else if (v > b1) { b1 = v; i1 = i; }
        }
        const float z   = expf(b1 - b0);
        const float inv = 1.f / (1.f + z);
        const int t = blk * 2 + tid;
        esc[t * 2 + 0] = inv;
        esc[t * 2 + 1] = z * inv;
        const int p0 = atomicAdd(&counts[i0], 1);
        if (p0 < LIST_CAP) lists[i0 * LIST_CAP + p0] = t * 2 + 0;
        const int p1 = atomicAdd(&counts[i1], 1);
        if (p1 < LIST_CAP) lists[i1 * LIST_CAP + p1] = t * 2 + 1;
    }
}

// ---------------------------------------------------------------------------
// Fused expert FFN, round 10: double-buffered LDS WEIGHT STAGING (bf16).
// grid (64 experts, 4 chunk-slots) = 256 blocks (1/CU), 1024 thr (4 w/SIMD).
// Every weight byte: loaded from global ONCE per block-chunk (fp32, coalesced
// f4), converted to bf16 (RNE), staged into a 2x16.6 KB LDS ring, and read
// from LDS by ALL tokens (register-path acc budget capped reuse at 4 — this
// removes that cap). x/v stay fp32 in LDS (broadcast reads). K split across
// lane-groups (r=lane>>4) with shfl_xor(16,32) reduce (R6's proven pattern).
// Exactly ONE global atomicAdd contribution per (slot, out-elem) — R9's
// partial-sum scatter atomics (4 XCD-separated writers/line) cost 1.36 GB.
// ---------------------------------------------------------------------------
__global__ __launch_bounds__(1024) void expert_kernel(
    const float* __restrict__ x,
    const float* __restrict__ w1s, const float* __restrict__ b1s,
    const float* __restrict__ w2s, const float* __restrict__ b2s,
    const int* __restrict__ counts, const int* __restrict__ lists,
    const float* __restrict__ esc, float* __restrict__ out)
{
    __shared__ __align__(16) float xs [T_GRP * XPAD];          // 16.0 KB
    __shared__ __align__(16) float vsm[T_GRP * VPAD];          //  8.3 KB
    __shared__ __align__(16) unsigned short wbuf[2][WBUF_SZ];  // 33.3 KB
    __shared__ int   slotIds[T_GRP];
    __shared__ float escv[T_GRP];

    const int e  = blockIdx.x;
    const int cs = blockIdx.y;
    const int ne = min(counts[e], LIST_CAP);
    const int nChunks = (ne + T_GRP - 1) / T_GRP;
    const int tid  = threadIdx.x;
    const int wave = tid >> 6, lane = tid & 63;
    const int c4 = lane & 15;        // f4-col within 16-col group
    const int r  = lane >> 4;        // K-subgroup 0..3 (4 consecutive rows)

    // phase-1 roles: 4 col-quarters x 4 token-pairs
    const int cq  = wave & 3,  tg1 = wave >> 2;
    const int co1 = cq * 16 + c4;            // f4-col in [0,64) of 256 hidden
    // phase-2 roles: 8 col-octants x 2 token-quads
    const int oct = wave & 7,  tg2 = wave >> 3;
    const int co2 = oct * 16 + c4;           // f4-col in [0,128) of 512 out

    const float4* w1f = (const float4*)(w1s + (size_t)e * IN_W * BLOCK_H);
    const float4* w2f = (const float4*)(w2s + (size_t)e * BLOCK_H * OUT_W);
    const float4* b1v = (const float4*)(b1s + (size_t)e * BLOCK_H);
    const float4* b2v = (const float4*)(b2s + (size_t)e * OUT_W);
    const float4* x4  = (const float4*)x;

    // staging store offsets (ushort index) for this thread's 2 f4-slots
    const int w1o0 = ((tid)        >> 6) * W1PAD + ((tid)        & 63) * 4;
    const int w1o1 = ((tid + 1024) >> 6) * W1PAD + ((tid + 1024) & 63) * 4;
    const int w2o0 = ((tid)        >> 7) * W2PAD + ((tid)        & 127) * 4;
    const int w2o1 = ((tid + 1024) >> 7) * W2PAD + ((tid + 1024) & 127) * 4;

    for (int ci = cs; ci < nChunks; ci += NCS) {
        const int base = ci * T_GRP;
        const int nTok = min(T_GRP, ne - base);
        if (tid < T_GRP) {
            const int s = (tid < nTok) ? lists[e * LIST_CAP + base + tid] : 0;
            slotIds[tid] = s;
            escv[tid]    = esc[s];
        }
        __syncthreads();

        // stage 8 token rows fp32 (zero-pad missing)
        for (int idx = tid; idx < T_GRP * 128; idx += 1024) {
            const int t = idx >> 7, q = idx & 127;
            float4 v = make_float4(0.f, 0.f, 0.f, 0.f);
            if (t < nTok) v = x4[(size_t)(slotIds[t] >> 1) * 128 + q];
            *(float4*)&xs[t * XPAD + q * 4] = v;
        }
        // prefetch slab 0 (W1) into registers (coalesced: lane-contiguous f4)
        float4 stA = w1f[tid];
        float4 stB = w1f[tid + 1024];

        float4 a1[2], a2[4];
        a1[0] = a1[1] = make_float4(0.f, 0.f, 0.f, 0.f);
        #pragma unroll
        for (int t = 0; t < 4; ++t) a2[t] = make_float4(0.f, 0.f, 0.f, 0.f);

        for (int s = 0; s < NSLAB; ++s) {
            unsigned short* buf = wbuf[s & 1];
            if (s) __syncthreads();          // consumers of this buffer done
            // ---- store staged slab (fp32 -> bf16 RNE) ----
            if (s < 16) {
                *(uint2*)&buf[w1o0] = packf4(stA);
                *(uint2*)&buf[w1o1] = packf4(stB);
            } else {
                *(uint2*)&buf[w2o0] = packf4(stA);
                *(uint2*)&buf[w2o1] = packf4(stB);
            }
            // ---- issue next slab's loads (2048 f4 per slab for both W1/W2) ----
            if (s + 1 < NSLAB) {
                const float4* src = (s + 1 < 16) ? (w1f + (size_t)(s + 1) * 2048)
                                                 : (w2f + (size_t)(s - 15) * 2048);
                stA = src[tid];
                stB = src[tid + 1024];
            }
            __syncthreads();                 // staged slab visible

            if (s < 16) {
                // ---- phase 1: accumulate x @ W1-slab ----
                const int kb = s * KS1;
                #pragma unroll
                for (int i = 0; i < 2; ++i) {
                    const int kw = i * 16 + r * 4;   // within-slab row base
                    const float4 xv0 = *(const float4*)&xs[(tg1*2+0) * XPAD + kb + kw];
                    const float4 xv1 = *(const float4*)&xs[(tg1*2+1) * XPAD + kb + kw];
                    #pragma unroll
                    for (int j = 0; j < 4; ++j) {
                        const uint2 u = *(const uint2*)&buf[(kw + j) * W1PAD + co1 * 4];
                        const float w0 = __uint_as_float(u.x << 16);
                        const float w1 = __uint_as_float(u.x & 0xFFFF0000u);
                        const float w2 = __uint_as_float(u.y << 16);
                        const float w3 = __uint_as_float(u.y & 0xFFFF0000u);
                        fma4(a1[0], ((const float*)&xv0)[j], w0, w1, w2, w3);
                        fma4(a1[1], ((const float*)&xv1)[j], w0, w1, w2, w3);
                    }
                }
                if (s == 15) {
                    // reduce K-partials across r lane-groups; bias+ReLU -> vsm
                    #pragma unroll
                    for (int m = 16; m <= 32; m <<= 1) {
                        #pragma unroll
                        for (int t = 0; t < 2; ++t) {
                            a1[t].x += __shfl_xor(a1[t].x, m);
                            a1[t].y += __shfl_xor(a1[t].y, m);
                            a1[t].z += __shfl_xor(a1[t].z, m);
                            a1[t].w += __shfl_xor(a1[t].w, m);
                        }
                    }
                    if (lane < 16) {
                        const float4 bb = b1v[co1];
                        #pragma unroll
                        for (int t = 0; t < 2; ++t) {
                            float4 rr;
                            rr.x = fmaxf(a1[t].x + bb.x, 0.f);
                            rr.y = fmaxf(a1[t].y + bb.y, 0.f);
                            rr.z = fmaxf(a1[t].z + bb.z, 0.f);
                            rr.w = fmaxf(a1[t].w + bb.w, 0.f);
                            *(float4*)&vsm[(tg1*2+t) * VPAD + co1 * 4] = rr;
                        }
                    }
                }
            } else {
                // ---- phase 2: accumulate v @ W2-slab ----
                const int s2 = s - 16;
                const int kw = r * 4;
                float4 vv[4];
                #pragma unroll
                for (int t = 0; t < 4; ++t)
                    vv[t] = *(const float4*)&vsm[(tg2*4+t) * VPAD + s2 * KS2 + kw];
                #pragma unroll
                for (int j = 0; j < 4; ++j) {
                    const uint2 u = *(const uint2*)&buf[(kw + j) * W2PAD + co2 * 4];
                    const float w0 = __uint_as_float(u.x << 16);
                    const float w1 = __uint_as_float(u.x & 0xFFFF0000u);
                    const float w2 = __uint_as_float(u.y << 16);
                    const float w3 = __uint_as_float(u.y & 0xFFFF0000u);
                    #pragma unroll
                    for (int t = 0; t < 4; ++t)
                        fma4(a2[t], ((const float*)&vv[t])[j], w0, w1, w2, w3);
                }
            }
        }

        // ---- epilogue: reduce K-partials, one atomic contribution/elem ----
        #pragma unroll
        for (int m = 16; m <= 32; m <<= 1) {
            #pragma unroll
            for (int t = 0; t < 4; ++t) {
                a2[t].x += __shfl_xor(a2[t].x, m);
                a2[t].y += __shfl_xor(a2[t].y, m);
                a2[t].z += __shfl_xor(a2[t].z, m);
                a2[t].w += __shfl_xor(a2[t].w, m);
            }
        }
        if (lane < 16) {
            const float4 bb = b2v[co2];
            #pragma unroll
            for (int t = 0; t < 4; ++t) {
                const int tt = tg2 * 4 + t;
                if (tt < nTok) {
                    const float sc = escv[tt];
                    float* o = out + (size_t)(slotIds[tt] >> 1) * OUT_W + co2 * 4;
                    atomicAdd(o + 0, (a2[t].x + bb.x) * sc);
                    atomicAdd(o + 1, (a2[t].y + bb.y) * sc);
                    atomicAdd(o + 2, (a2[t].z + bb.z) * sc);
                    atomicAdd(o + 3, (a2[t].w + bb.w) * sc);
                }
            }
        }
        __syncthreads();   // xs/vsm/slotIds reused next chunk (ne > 32 only)
    }
}

extern "C" void kernel_launch(void* const* d_in, const int* in_sizes, int n_in,
                              void* d_out, int out_size, void* d_ws, size_t ws_size,
                              hipStream_t stream) {
    const float* x      = (const float*)d_in[0];
    const float* noise  = (const float*)d_in[1];
    const float* w1s    = (const float*)d_in[2];
    const float* b1s    = (const float*)d_in[3];
    const float* w2s    = (const float*)d_in[4];
    const float* b2s    = (const float*)d_in[5];
    const float* mixer  = (const float*)d_in[6];
    const float* noisec = (const float*)d_in[7];
    float* out = (float*)d_out;

    // workspace: ~41 KB total (keep far under ws_size; round 2's 2.2 MB
    // layout overran d_ws and corrupted adjacent allocations)
    char* ws = (char*)d_ws;
    int*   counts = (int*)ws;                       ws += 256;
    float* esc    = (float*)ws;                     ws += NSLOTS * sizeof(float);
    int*   lists  = (int*)ws;   /* 64 * 128 ints = 32 KB */

    hipMemsetAsync(d_out, 0, (size_t)out_size * sizeof(float), stream);
    hipMemsetAsync(counts, 0, 256, stream);

    routing_kernel<<<TOKENS / 2, 256, 0, stream>>>(x, noise, mixer, noisec,
                                                   esc, counts, lists);
    expert_kernel<<<dim3(N_EXPERTS, NCS), 1024, 0, stream>>>(
        x, w1s, b1s, w2s, b2s, counts, lists, esc, out);
}